// Round 1
// baseline (113.988 us; speedup 1.0000x reference)
//
#include <hip/hip_runtime.h>
#include <cstddef>

constexpr int NGF    = 80;
constexpr int TLEN   = 1000;
constexpr int SPLICE = 10;
constexpr int PATCH  = 2 * SPLICE + 1;  // 21
constexpr int NH     = 50;
constexpr int BT     = 256;             // t per block

__global__ __launch_bounds__(BT) void relevance_fwd(
    const float* __restrict__ x,    // [B, NGF, TLEN]
    const float* __restrict__ W1,   // [NH, PATCH]
    const float* __restrict__ b1,   // [NH]
    const float* __restrict__ W2,   // [NH]  (shape [1,NH])
    const float* __restrict__ b2,   // [1]
    float* __restrict__ out)        // [B, TLEN, NGF]
{
    const int tid = threadIdx.x;
    const int t0  = blockIdx.x * BT;
    const int f   = blockIdx.y;
    const int b   = blockIdx.z;

    __shared__ float s[BT + 2 * SPLICE];  // x segment covering [t0-10, t0+BT+10)

    const float* xrow = x + ((size_t)b * NGF + f) * TLEN;

    // stage padded segment: s[i] = xp[t0 - SPLICE + i] (zeros outside [0,TLEN))
    int g = t0 - SPLICE + tid;
    s[tid] = (g >= 0 && g < TLEN) ? xrow[g] : 0.0f;
    if (tid < 2 * SPLICE) {
        int g2 = g + BT;
        s[BT + tid] = (g2 >= 0 && g2 < TLEN) ? xrow[g2] : 0.0f;
    }
    __syncthreads();

    const int t = t0 + tid;
    if (t >= TLEN) return;

    // patch into registers: thread t uses s[tid .. tid+20]
    float p[PATCH];
    #pragma unroll
    for (int k = 0; k < PATCH; ++k) p[k] = s[tid + k];

    float z = b2[0];
    #pragma unroll 2
    for (int j = 0; j < NH; ++j) {
        float acc = b1[j];                 // uniform -> s_load
        #pragma unroll
        for (int k = 0; k < PATCH; ++k)
            acc = fmaf(W1[j * PATCH + k], p[k], acc);  // uniform W1 -> s_load
        float h = __fdividef(1.0f, 1.0f + __expf(-acc));
        z = fmaf(W2[j], h, z);
    }
    out[((size_t)b * TLEN + t) * NGF + f] = __fdividef(1.0f, 1.0f + __expf(-z));
}

extern "C" void kernel_launch(void* const* d_in, const int* in_sizes, int n_in,
                              void* d_out, int out_size, void* d_ws, size_t ws_size,
                              hipStream_t stream) {
    const float* x  = (const float*)d_in[0];
    const float* W1 = (const float*)d_in[1];
    const float* b1 = (const float*)d_in[2];
    const float* W2 = (const float*)d_in[3];
    const float* b2 = (const float*)d_in[4];
    float* out = (float*)d_out;

    const int B = in_sizes[0] / (NGF * TLEN);  // 32

    dim3 grid((TLEN + BT - 1) / BT, NGF, B);   // (4, 80, 32)
    relevance_fwd<<<grid, BT, 0, stream>>>(x, W1, b1, W2, b2, out);
}